// Round 13
// baseline (1117.672 us; speedup 1.0000x reference)
//
#include <hip/hip_runtime.h>
#include <hip/hip_bf16.h>

#define NIN    512
#define NEVAL  1536
#define NCOLS  2048
#define NOUT   256
#define OUT_BASE 1280
#define NBLK   48       // NEVAL / 32

typedef __attribute__((ext_vector_type(8))) short short8;   // 8 bf16 (4 VGPRs)
typedef __attribute__((ext_vector_type(4))) float floatx4;  // MFMA C/D

// ---------- helpers ----------

__device__ __forceinline__ unsigned short f2bf(float f) {
    __hip_bfloat16 h = __float2bfloat16(f);
    return __builtin_bit_cast(unsigned short, h);
}
__device__ __forceinline__ unsigned pack2(float a, float b) {
    return (unsigned)f2bf(a) | ((unsigned)f2bf(b) << 16);
}
// sigmoid(clip(5z,-60,60)): clamp dropped — v_exp overflow gives exact 0/1.
__device__ __forceinline__ float sigmoid5(float z) {
    return __builtin_amdgcn_rcpf(1.0f + __expf(-5.0f * z));
}

// ---------- W fp32 -> bf16 (d_ws re-poisoned every launch, so rerun) ----------

__global__ __launch_bounds__(256) void wconv(const float* __restrict__ W,
                                             ushort* __restrict__ Wb, int n8) {
    int i = blockIdx.x * blockDim.x + threadIdx.x;
    if (i < n8) {
        float4 v0 = ((const float4*)W)[2 * i];
        float4 v1 = ((const float4*)W)[2 * i + 1];
        uint4 pk;
        pk.x = pack2(v0.x, v0.y); pk.y = pack2(v0.z, v0.w);
        pk.z = pack2(v1.x, v1.y); pk.w = pack2(v1.z, v1.w);
        ((uint4*)Wb)[i] = pk;
    }
}

// ---------- main kernel ----------
// 256 WGs x 1024 threads (16 waves), 1 WG/CU. WG owns 16 rows.
// ROUND-13: single-wave chain. R2-R12 invariance traced to the chain phase:
// 16 waves each redundantly running the serial chain (~10K cyc/SIMD/block of
// transcendental+readlane+Wt-read issue). New chain: wave 0 only, lane r =
// row r, z[32] in REGISTERS per lane. Step j: o = sigmoid(z[j]) (own reg —
// no cross-lane on serial path!), then z[i] += w[i][j]*o for i>j with w via
// uniform-address ds_read_b128 broadcast (4-granular triangle; w[i][j]=0 for
// i<=j makes over-read harmless). Other 15 waves issue main(k+1) then park
// at barrier A — drains overlap the chain.
// Per 32-node block k (cols [L0, L0+32), L0 = 512+32k):
//   A: barrier — chain(k-1) O/Wt/Zfin-reads done
//   all: Wt stage (Wt[col*36+node], 16B-aligned 4-groups), main(k+1) MFMAs,
//        tail MFMA (owner ksp==(k+7)&7), Zred write
//   B: barrier — Zred visible
//   all: gather 8 partials + bias -> Zfin[node*17+row] (transposed)
//   C: barrier — Zfin visible
//   wave0: chain; writes o -> O (bf16) and out (global) per step

__global__ __launch_bounds__(1024) void ffnet(const float* __restrict__ x,
                                              const float* __restrict__ W,
                                              const ushort* __restrict__ Wb,
                                              const float* __restrict__ bias,
                                              float* __restrict__ out) {
    __shared__ unsigned short O[16 * 2048];   // 64 KB
    __shared__ float Zred[16 * 256];          // 16 KB [wave][lane][reg]
    __shared__ float Wt[32 * 36];             // 4.6 KB diag, Wt[j*36+i]
    __shared__ float Zfin[32 * 17];           // 2.2 KB z-init, [node*17+row]

    const int t    = threadIdx.x;
    const int w    = t >> 6;        // wave 0..15
    const int lane = t & 63;

    // phase-A role (R8 mapping): 2 node-halves x 8 K-split slots
    const int m16  = lane & 15;     // A row (batch row) / D col (node)
    const int quad = lane >> 4;     // 0..3
    const int half = w >> 3;        // 0..1
    const int ksp  = w & 7;         // 0..7
    const int arow = m16 << 11;
    const int arot = m16 << 3;

    const int ii   = lane & 31;     // node within block (gather role)
    const long row = (long)blockIdx.x * 16 + w;
    const int rot  = w << 3;

    // chain role (wave 0): lane r = batch row
    const int r16  = lane & 15;

    // Wt staging role: one float per thread
    const int sn = t >> 5;          // 0..31 node i
    const int sc = t & 31;          // 0..31 col j

    // ---- stage x row w into LDS as bf16 (swizzled) ----
    {
        const float* xr = x + row * NIN + lane * 8;
        float4 v0 = *(const float4*)xr;
        float4 v1 = *(const float4*)(xr + 4);
        uint4 pk;
        pk.x = pack2(v0.x, v0.y); pk.y = pack2(v0.z, v0.w);
        pk.z = pack2(v1.x, v1.y); pk.w = pack2(v1.z, v1.w);
        *(uint4*)&O[(w << 11) + ((lane * 8 + rot) & 2047)] = pk;
    }
    __syncthreads();

    // ---- prologue: main(0) over columns [0, 480) ----
    floatx4 acc = {0.f, 0.f, 0.f, 0.f};
    {
        const ushort* wb = Wb + (size_t)(half * 16 + m16) * NCOLS;
        for (int kk = ksp * 32; kk < NIN - 32; kk += 256) {
            short8 a = *(const short8*)&O[arow + ((kk + quad * 8 + arot) & 2047)];
            short8 b = *(const short8*)&wb[kk + quad * 8];
            acc = __builtin_amdgcn_mfma_f32_16x16x32_bf16(a, b, acc, 0, 0, 0);
        }
    }

    for (int k = 0; k < NBLK; ++k) {
        const int i0 = k << 5;
        const int L0 = NIN + i0;
        const int g  = i0 + ii;

        __syncthreads();            // barrier A

        // Wt diag load (1 float/thread) + bias, issued early
        float wtv = W[(size_t)(i0 + sn) * NCOLS + L0 + sc];
        float bi  = bias[g];

        // main(k+1) over [0, L0) — drains overlap Wt stage / barrier B / chain
        floatx4 accN = {0.f, 0.f, 0.f, 0.f};
        if (k + 1 < NBLK) {
            const ushort* wb = Wb + (size_t)(i0 + 32 + half * 16 + m16) * NCOLS;
            #pragma unroll 2
            for (int kk = ksp * 32; kk < L0; kk += 256) {
                short8 a = *(const short8*)&O[arow + ((kk + quad * 8 + arot) & 2047)];
                short8 b = *(const short8*)&wb[kk + quad * 8];
                accN = __builtin_amdgcn_mfma_f32_16x16x32_bf16(a, b, accN, 0, 0, 0);
            }
        }

        // stage diag weights: Wt[j*36 + i] (j=col, i=node; stride 36 keeps
        // 4-aligned i groups 16B-aligned for ds_read_b128)
        Wt[sc * 36 + sn] = wtv;

        // tail: K=32 MFMA over [L0-32, L0) — chunk 15+k, owner ksp=(k+7)&7
        if (ksp == ((k + 7) & 7)) {
            const ushort* wb = Wb + (size_t)(i0 + half * 16 + m16) * NCOLS;
            const int ts = L0 - 32;
            short8 a = *(const short8*)&O[arow + ((ts + quad * 8 + arot) & 2047)];
            short8 b = *(const short8*)&wb[ts + quad * 8];
            acc = __builtin_amdgcn_mfma_f32_16x16x32_bf16(a, b, acc, 0, 0, 0);
        }

        // D frag: lane q*16+n holds Z[m=4q+reg][n]
        *(floatx4*)&Zred[(w << 8) + (lane << 2)] = acc;
        __syncthreads();            // barrier B

        // gather z-init for (row w, node ii) -> Zfin[ii*17 + w]
        {
            const int h = ii >> 4, n = ii & 15;
            const int ridx = ((w >> 2) << 6) + (n << 2) + (w & 3);
            float zacc = bi;
            #pragma unroll
            for (int p = 0; p < 8; ++p)
                zacc += Zred[(((h << 3) + p) << 8) + ridx];
            if (lane < 32)
                Zfin[ii * 17 + w] = zacc;
        }
        __syncthreads();            // barrier C: Zfin visible

        // ---- chain: wave 0 only, lane r16 = row, z[32] in registers ----
        if (w == 0) {
            float z[32];
            #pragma unroll
            for (int i = 0; i < 32; ++i)
                z[i] = Zfin[i * 17 + r16];

            #pragma unroll
            for (int j = 0; j < 32; ++j) {
                float o = sigmoid5(z[j]);
                if (lane < 16) {
                    O[(r16 << 11) + ((L0 + j + (r16 << 3)) & 2047)] = f2bf(o);
                    int gg = i0 + j;
                    if (gg >= OUT_BASE)
                        out[((long)blockIdx.x * 16 + r16) * NOUT +
                            (gg - OUT_BASE)] = o;
                }
                #pragma unroll
                for (int g4 = (j + 1) >> 2; g4 < 8; ++g4) {
                    float4 wq = *(const float4*)&Wt[j * 36 + g4 * 4];
                    z[g4 * 4 + 0] = fmaf(wq.x, o, z[g4 * 4 + 0]);
                    z[g4 * 4 + 1] = fmaf(wq.y, o, z[g4 * 4 + 1]);
                    z[g4 * 4 + 2] = fmaf(wq.z, o, z[g4 * 4 + 2]);
                    z[g4 * 4 + 3] = fmaf(wq.w, o, z[g4 * 4 + 3]);
                }
            }
        }
        acc = accN;
    }
}

// ---------- launch ----------

extern "C" void kernel_launch(void* const* d_in, const int* in_sizes, int n_in,
                              void* d_out, int out_size, void* d_ws, size_t ws_size,
                              hipStream_t stream) {
    const float* x  = (const float*)d_in[0];   // [4096, 512]
    const float* W  = (const float*)d_in[1];   // [1536, 2048]
    const float* b  = (const float*)d_in[2];   // [1536]
    float* out = (float*)d_out;                // [4096, 256]
    ushort* Wb = (ushort*)d_ws;                // bf16 W copy (6.3 MB)

    int n8 = NEVAL * NCOLS / 8;
    wconv<<<n8 / 256, 256, 0, stream>>>(W, Wb, n8);
    ffnet<<<4096 / 16, 1024, 0, stream>>>(x, W, Wb, b, out);
}